// Round 1
// baseline (803.013 us; speedup 1.0000x reference)
//
#include <hip/hip_runtime.h>

#define K_DIM 40960
#define NFEAT 256
#define BATCH 2048

typedef _Float16 f16;
typedef _Float16 f16x8 __attribute__((ext_vector_type(8)));
typedef _Float16 f16x4 __attribute__((ext_vector_type(4)));
typedef float f32x4 __attribute__((ext_vector_type(4)));

// ---------------- Kernel 0: W fp32 -> fp16 ----------------
__global__ __launch_bounds__(256) void convert_w(
    const float* __restrict__ w1p, const float* __restrict__ w1o,
    f16* __restrict__ w16p, f16* __restrict__ w16o) {
  const long N4 = (long)NFEAT * K_DIM / 4;  // float4s per matrix
  long stride = (long)gridDim.x * blockDim.x;
  for (long i = (long)blockIdx.x * blockDim.x + threadIdx.x; i < 2 * N4; i += stride) {
    const float4* src;
    f16* dst;
    long idx;
    if (i < N4) { src = (const float4*)w1p; dst = w16p; idx = i; }
    else        { src = (const float4*)w1o; dst = w16o; idx = i - N4; }
    float4 v = src[idx];
    f16x4 h;
    h.x = (f16)v.x; h.y = (f16)v.y; h.z = (f16)v.z; h.w = (f16)v.w;
    *(f16x4*)(dst + idx * 4) = h;
  }
}

// ---------------- Kernel 1: feature-transformer GEMM (split-K, fp16 MFMA) ----
// Block: 64 rows (batch) x 256 cols (features) for one perspective, K-range = K_DIM/S.
// Grid: (2048/64) * S * 2 blocks.  partial[persp][s][row][col] fp32.
__global__ __launch_bounds__(256, 2) void ft_gemm(
    const float* __restrict__ Ap, const float* __restrict__ Ao,
    const f16* __restrict__ W16p, const f16* __restrict__ W16o,
    const float* __restrict__ W32p, const float* __restrict__ W32o,
    int use_w16, int S, float* __restrict__ partials) {
  __shared__ f16 Ash[64 * 72];    // +8 halves pad per row
  __shared__ f16 Wsh[256 * 64];   // XOR-swizzled 16B blocks

  int b = blockIdx.x;
  int persp = b & 1;
  int t = b >> 1;
  int s = t % S;
  int mt = t / S;
  int mbase = mt * 64;

  const float* A = persp ? Ao : Ap;
  const f16* W16 = persp ? W16o : W16p;
  const float* W32 = persp ? W32o : W32p;

  int tid = threadIdx.x;
  int lane = tid & 63;
  int wv = tid >> 6;        // wave id 0..3 -> cols [wv*64, wv*64+64)
  int mrow = lane & 15;
  int kq = lane >> 4;       // 0..3

  f32x4 acc[4][4];
#pragma unroll
  for (int rt = 0; rt < 4; ++rt)
#pragma unroll
    for (int ct = 0; ct < 4; ++ct)
      acc[rt][ct] = (f32x4){0.f, 0.f, 0.f, 0.f};

  const int krange = K_DIM / S;
  const int kstart = s * krange;

  for (int k0 = kstart; k0 < kstart + krange; k0 += 64) {
    // ---- stage A chunk: 64 rows x 64 k fp32 -> fp16 LDS (padded rows) ----
#pragma unroll
    for (int i = 0; i < 4; ++i) {
      int f = i * 256 + tid;          // 0..1023 float4-slots
      int row = f >> 4;               // 0..63
      int cb = f & 15;                // 16 float4s per row
      float4 v = *(const float4*)(A + (size_t)(mbase + row) * K_DIM + k0 + cb * 4);
      f16x4 h;
      h.x = (f16)v.x; h.y = (f16)v.y; h.z = (f16)v.z; h.w = (f16)v.w;
      *(f16x4*)&Ash[row * 72 + cb * 4] = h;
    }
    // ---- stage W chunk: 256 rows x 64 k fp16, XOR-swizzled ----
    if (use_w16) {
#pragma unroll
      for (int i = 0; i < 8; ++i) {
        int f = i * 256 + tid;        // 0..2047 16B-slots
        int rl = f >> 3;              // 0..255
        int kbs = f & 7;              // slot within row
        int kbg = kbs ^ (rl & 7);     // global 16B-block
        f16x8 v = *(const f16x8*)(W16 + (size_t)rl * K_DIM + k0 + kbg * 8);
        *(f16x8*)&Wsh[rl * 64 + kbs * 8] = v;
      }
    } else {
#pragma unroll
      for (int i = 0; i < 8; ++i) {
        int f = i * 256 + tid;
        int rl = f >> 3;
        int kbs = f & 7;
        int kbg = kbs ^ (rl & 7);
        const float* src = W32 + (size_t)rl * K_DIM + k0 + kbg * 8;
        float4 v0 = *(const float4*)(src);
        float4 v1 = *(const float4*)(src + 4);
        f16x8 h;
        h[0] = (f16)v0.x; h[1] = (f16)v0.y; h[2] = (f16)v0.z; h[3] = (f16)v0.w;
        h[4] = (f16)v1.x; h[5] = (f16)v1.y; h[6] = (f16)v1.z; h[7] = (f16)v1.w;
        *(f16x8*)&Wsh[rl * 64 + kbs * 8] = h;
      }
    }
    __syncthreads();

    // ---- MFMA: 4 row-tiles x 4 col-tiles, 2 k-steps of 32 ----
#pragma unroll
    for (int ks = 0; ks < 2; ++ks) {
      f16x8 afrag[4], bfrag[4];
#pragma unroll
      for (int rt = 0; rt < 4; ++rt)
        afrag[rt] = *(const f16x8*)&Ash[(rt * 16 + mrow) * 72 + ks * 32 + kq * 8];
#pragma unroll
      for (int ct = 0; ct < 4; ++ct) {
        int rown = wv * 64 + ct * 16 + mrow;   // feature row (= B col)
        int kb = ks * 4 + kq;
        int kbp = kb ^ (rown & 7);
        bfrag[ct] = *(const f16x8*)&Wsh[rown * 64 + kbp * 8];
      }
#pragma unroll
      for (int rt = 0; rt < 4; ++rt)
#pragma unroll
        for (int ct = 0; ct < 4; ++ct)
          acc[rt][ct] = __builtin_amdgcn_mfma_f32_16x16x32_f16(
              afrag[rt], bfrag[ct], acc[rt][ct], 0, 0, 0);
    }
    __syncthreads();
  }

  // ---- epilogue: write fp32 partials ----
  float* pp = partials + ((size_t)persp * S + s) * ((size_t)BATCH * NFEAT);
#pragma unroll
  for (int rt = 0; rt < 4; ++rt)
#pragma unroll
    for (int ct = 0; ct < 4; ++ct) {
      int col = wv * 64 + ct * 16 + mrow;
#pragma unroll
      for (int i = 0; i < 4; ++i) {
        int row = mbase + rt * 16 + kq * 4 + i;
        pp[(size_t)row * NFEAT + col] = acc[rt][ct][i];
      }
    }
}

// ---------------- Kernel 2: reduce partials + bias + clip -> combined ------
__global__ __launch_bounds__(256) void reduce_bias(
    const float* __restrict__ partials, const float* __restrict__ b1p,
    const float* __restrict__ b1o, int S, float* __restrict__ combined) {
  int idx = blockIdx.x * blockDim.x + threadIdx.x;  // 2048*512
  int r = idx >> 9;
  int c = idx & 511;
  int persp = c >> 8;
  int n = c & 255;
  float sum = persp ? b1o[n] : b1p[n];
  const float* p = partials + (size_t)persp * S * BATCH * NFEAT + (size_t)r * NFEAT + n;
  for (int s = 0; s < S; ++s) sum += p[(size_t)s * BATCH * NFEAT];
  sum = fminf(fmaxf(sum, 0.f), 1.f);
  combined[(size_t)r * 512 + c] = sum;
}

// ---------------- Kernel 3: fused small MLP (layers 2..4) ------------------
__global__ __launch_bounds__(256) void mlp(
    const float* __restrict__ combined, const float* __restrict__ W2,
    const float* __restrict__ b2, const float* __restrict__ W3,
    const float* __restrict__ b3, const float* __restrict__ Wo,
    const float* __restrict__ bo, float* __restrict__ out) {
  __shared__ float H1s[8][33];
  __shared__ float H2s[8][33];
  int tid = threadIdx.x;
  int lr = tid >> 5;   // 0..7 local row
  int j = tid & 31;    // output feature
  int r = blockIdx.x * 8 + lr;

  const float* crow = combined + (size_t)r * 512;
  const float* w2r = W2 + j * 512;
  float acc = b2[j];
#pragma unroll 8
  for (int k = 0; k < 512; ++k) acc += crow[k] * w2r[k];
  H1s[lr][j] = fminf(fmaxf(acc, 0.f), 1.f);
  __syncthreads();

  acc = b3[j];
  const float* w3r = W3 + j * 32;
#pragma unroll
  for (int k = 0; k < 32; ++k) acc += H1s[lr][k] * w3r[k];
  H2s[lr][j] = fminf(fmaxf(acc, 0.f), 1.f);
  __syncthreads();

  if (j == 0) {
    float o = bo[0];
#pragma unroll
    for (int k = 0; k < 32; ++k) o += H2s[lr][k] * Wo[k];
    out[r] = fminf(fmaxf(o, 0.f), 1.f);
  }
}

// ---------------- launch ----------------
extern "C" void kernel_launch(void* const* d_in, const int* in_sizes, int n_in,
                              void* d_out, int out_size, void* d_ws, size_t ws_size,
                              hipStream_t stream) {
  const float* Ap  = (const float*)d_in[0];
  const float* Ao  = (const float*)d_in[1];
  const float* W1p = (const float*)d_in[2];
  const float* b1p = (const float*)d_in[3];
  const float* W1o = (const float*)d_in[4];
  const float* b1o = (const float*)d_in[5];
  const float* W2  = (const float*)d_in[6];
  const float* b2  = (const float*)d_in[7];
  const float* W3  = (const float*)d_in[8];
  const float* b3  = (const float*)d_in[9];
  const float* Wo  = (const float*)d_in[10];
  const float* bo  = (const float*)d_in[11];
  float* out = (float*)d_out;

  const size_t W16B = 2UL * NFEAT * K_DIM * 2;     // 41.9 MB
  const size_t COMB = (size_t)BATCH * 512 * 4;     // 4.2 MB
  auto need = [&](int s, int w16) {
    return (w16 ? W16B : 0) + (size_t)s * 2 * BATCH * NFEAT * 4 + COMB;
  };

  int S = 8, use_w16 = 1;
  while (S > 1 && need(S, 1) > ws_size) S >>= 1;
  if (need(S, 1) > ws_size) {
    use_w16 = 0;
    S = 8;
    while (S > 1 && need(S, 0) > ws_size) S >>= 1;
  }

  char* ws = (char*)d_ws;
  f16* W16p = (f16*)ws;
  f16* W16o = W16p + (size_t)NFEAT * K_DIM;
  float* partials = (float*)(ws + (use_w16 ? W16B : 0));
  float* combined = partials + (size_t)S * 2 * BATCH * NFEAT;

  if (use_w16)
    convert_w<<<1024, 256, 0, stream>>>(W1p, W1o, W16p, W16o);

  int grid = (BATCH / 64) * S * 2;
  ft_gemm<<<grid, 256, 0, stream>>>(Ap, Ao, W16p, W16o, W1p, W1o, use_w16, S, partials);

  reduce_bias<<<(BATCH * 512) / 256, 256, 0, stream>>>(partials, b1p, b1o, S, combined);

  mlp<<<BATCH / 8, 256, 0, stream>>>(combined, W2, b2, W3, b3, Wo, bo, out);
}

// Round 2
// 776.358 us; speedup vs baseline: 1.0343x; 1.0343x over previous
//
#include <hip/hip_runtime.h>

#define K_DIM 40960
#define NFEAT 256
#define BATCH 2048

typedef _Float16 f16;
typedef _Float16 f16x8 __attribute__((ext_vector_type(8)));
typedef _Float16 f16x4 __attribute__((ext_vector_type(4)));
typedef _Float16 f16x2 __attribute__((ext_vector_type(2)));
typedef float f32x4 __attribute__((ext_vector_type(4)));

// ---------------- Kernel 0: W fp32 -> fp16 ----------------
__global__ __launch_bounds__(256) void convert_w(
    const float* __restrict__ w1p, const float* __restrict__ w1o,
    f16* __restrict__ w16p, f16* __restrict__ w16o) {
  const long N4 = (long)NFEAT * K_DIM / 4;  // float4s per matrix
  long stride = (long)gridDim.x * blockDim.x;
  for (long i = (long)blockIdx.x * blockDim.x + threadIdx.x; i < 2 * N4; i += stride) {
    const float4* src;
    f16* dst;
    long idx;
    if (i < N4) { src = (const float4*)w1p; dst = w16p; idx = i; }
    else        { src = (const float4*)w1o; dst = w16o; idx = i - N4; }
    float4 v = src[idx];
    f16x4 h;
    h[0] = (f16)v.x; h[1] = (f16)v.y; h[2] = (f16)v.z; h[3] = (f16)v.w;
    *(f16x4*)(dst + idx * 4) = h;
  }
}

// ---------------- Kernel 1: feature-transformer GEMM ----------------
// 512 threads = 8 waves; tile 64 rows x 256 cols; K-chunk 64; split-K S slices.
// LDS exactly 40960 B -> 2 blocks/CU (16 waves/CU). Register-prefetch pipeline.
// Block index: b = mt*(2S) + g, g = s*2+persp  -> b%8 fixes g%8, so each XCD's
// L2 holds few W slices (W re-reads L2-local; HBM reserved for the A stream).
__global__ __launch_bounds__(512, 4) void ft_gemm(
    const float* __restrict__ Ap, const float* __restrict__ Ao,
    const f16* __restrict__ W16p, const f16* __restrict__ W16o,
    int S, f16* __restrict__ partials) {
  __shared__ f16 Ash[64 * 64];    // XOR-swizzled 16B blocks: slot = blk ^ (row&7)
  __shared__ f16 Wsh[256 * 64];   // XOR-swizzled 16B blocks

  const int b = blockIdx.x;
  const int G = 2 * S;
  const int g = b % G;
  const int mt = b / G;
  const int persp = g & 1;
  const int s = g >> 1;
  const int mbase = mt * 64;

  const float* A = persp ? Ao : Ap;
  const f16* W16 = persp ? W16o : W16p;

  const int tid = threadIdx.x;
  const int lane = tid & 63;
  const int wv = tid >> 6;      // 0..7, wave owns cols [wv*32, wv*32+32)
  const int mrow = lane & 15;
  const int kq = lane >> 4;     // 0..3

  f32x4 acc[4][2];
#pragma unroll
  for (int rt = 0; rt < 4; ++rt)
#pragma unroll
    for (int ct = 0; ct < 2; ++ct)
      acc[rt][ct] = (f32x4){0.f, 0.f, 0.f, 0.f};

  const int krange = K_DIM / S;
  const int kstart = s * krange;
  const int kend = kstart + krange;

  // staging indices (precomputed, loop-invariant)
  int a_row[2], a_cb[2];
#pragma unroll
  for (int i = 0; i < 2; ++i) { int f = i * 512 + tid; a_row[i] = f >> 4; a_cb[i] = f & 15; }
  int w_rl[4], w_kbs[4], w_kbg[4];
#pragma unroll
  for (int i = 0; i < 4; ++i) {
    int f = i * 512 + tid; w_rl[i] = f >> 3; w_kbs[i] = f & 7; w_kbg[i] = w_kbs[i] ^ (w_rl[i] & 7);
  }

  float4 pa[2];
  f16x8 pw[4];
  // prologue prefetch
#pragma unroll
  for (int i = 0; i < 2; ++i)
    pa[i] = *(const float4*)(A + (size_t)(mbase + a_row[i]) * K_DIM + kstart + a_cb[i] * 4);
#pragma unroll
  for (int i = 0; i < 4; ++i)
    pw[i] = *(const f16x8*)(W16 + (size_t)w_rl[i] * K_DIM + kstart + w_kbg[i] * 8);

  for (int k0 = kstart; k0 < kend; k0 += 64) {
    // ---- drain prefetched regs into LDS ----
#pragma unroll
    for (int i = 0; i < 2; ++i) {
      int row = a_row[i], cb = a_cb[i];
      int slot = (cb >> 1) ^ (row & 7);
      f16x4 h;
      h[0] = (f16)pa[i].x; h[1] = (f16)pa[i].y; h[2] = (f16)pa[i].z; h[3] = (f16)pa[i].w;
      *(f16x4*)&Ash[row * 64 + slot * 8 + (cb & 1) * 4] = h;
    }
#pragma unroll
    for (int i = 0; i < 4; ++i)
      *(f16x8*)&Wsh[w_rl[i] * 64 + w_kbs[i] * 8] = pw[i];
    __syncthreads();

    // ---- issue next chunk's loads (unconditional, clamped) ----
    const int kn = (k0 + 64 < kend) ? (k0 + 64) : kstart;
#pragma unroll
    for (int i = 0; i < 2; ++i)
      pa[i] = *(const float4*)(A + (size_t)(mbase + a_row[i]) * K_DIM + kn + a_cb[i] * 4);
#pragma unroll
    for (int i = 0; i < 4; ++i)
      pw[i] = *(const f16x8*)(W16 + (size_t)w_rl[i] * K_DIM + kn + w_kbg[i] * 8);

    // ---- MFMA on current LDS tile ----
#pragma unroll
    for (int ks = 0; ks < 2; ++ks) {
      const int kb = ks * 4 + kq;
      f16x8 af[4], bf[2];
#pragma unroll
      for (int rt = 0; rt < 4; ++rt) {
        int row = rt * 16 + mrow;
        af[rt] = *(const f16x8*)&Ash[row * 64 + (kb ^ (row & 7)) * 8];
      }
#pragma unroll
      for (int ct = 0; ct < 2; ++ct) {
        int rown = (wv * 2 + ct) * 16 + mrow;
        bf[ct] = *(const f16x8*)&Wsh[rown * 64 + (kb ^ (rown & 7)) * 8];
      }
#pragma unroll
      for (int rt = 0; rt < 4; ++rt)
#pragma unroll
        for (int ct = 0; ct < 2; ++ct)
          acc[rt][ct] = __builtin_amdgcn_mfma_f32_16x16x32_f16(af[rt], bf[ct], acc[rt][ct], 0, 0, 0);
    }
    __syncthreads();
  }

  // ---- epilogue: fp16 partials, slice index = g ----
  f16* pp = partials + (size_t)g * ((size_t)BATCH * NFEAT);
#pragma unroll
  for (int rt = 0; rt < 4; ++rt)
#pragma unroll
    for (int ct = 0; ct < 2; ++ct) {
      int col = (wv * 2 + ct) * 16 + mrow;
#pragma unroll
      for (int i = 0; i < 4; ++i) {
        int row = mbase + rt * 16 + kq * 4 + i;
        pp[(size_t)row * NFEAT + col] = (f16)acc[rt][ct][i];
      }
    }
}

// ---------------- Kernel 2: reduce partials + bias + clip -> combined ------
__global__ __launch_bounds__(256) void reduce_bias(
    const f16* __restrict__ partials, const float* __restrict__ b1p,
    const float* __restrict__ b1o, int S, float* __restrict__ combined) {
  int idx = blockIdx.x * 256 + threadIdx.x;   // 2048 * 256 (2 cols each)
  int r = idx >> 8;
  int c2 = idx & 255;
  int persp = c2 >> 7;
  int n = (c2 & 127) * 2;
  const float* bias = persp ? b1o : b1p;
  float s0 = bias[n], s1 = bias[n + 1];
#pragma unroll 4
  for (int s = 0; s < S; ++s) {
    f16x2 v = *(const f16x2*)(partials + ((size_t)(s * 2 + persp)) * BATCH * NFEAT +
                              (size_t)r * NFEAT + n);
    s0 += (float)v[0]; s1 += (float)v[1];
  }
  s0 = fminf(fmaxf(s0, 0.f), 1.f);
  s1 = fminf(fmaxf(s1, 0.f), 1.f);
  float2 o; o.x = s0; o.y = s1;
  *(float2*)(combined + (size_t)r * 512 + persp * 256 + n) = o;
}

// ---------------- Kernel 3: fused small MLP (layers 2..4) ------------------
__global__ __launch_bounds__(256) void mlp(
    const float* __restrict__ combined, const float* __restrict__ W2,
    const float* __restrict__ b2, const float* __restrict__ W3,
    const float* __restrict__ b3, const float* __restrict__ Wo,
    const float* __restrict__ bo, float* __restrict__ out) {
  __shared__ f16 W2T[512 * 33];   // [k][j], padded: 2-way max bank aliasing
  __shared__ float H1s[8][33];
  __shared__ float H2s[8][33];
  int tid = threadIdx.x;
#pragma unroll
  for (int i = 0; i < 64; ++i) {
    int idx = i * 256 + tid;
    int j = idx >> 9;
    int k = idx & 511;
    W2T[k * 33 + j] = (f16)W2[idx];
  }
  __syncthreads();

  int lr = tid >> 5;   // 0..7 local row
  int j = tid & 31;    // output feature
  int r = blockIdx.x * 8 + lr;

  const float* crow = combined + (size_t)r * 512;
  float acc = b2[j];
#pragma unroll 8
  for (int k = 0; k < 512; ++k) acc += crow[k] * (float)W2T[k * 33 + j];
  H1s[lr][j] = fminf(fmaxf(acc, 0.f), 1.f);
  __syncthreads();

  acc = b3[j];
  const float* w3r = W3 + j * 32;
#pragma unroll
  for (int k = 0; k < 32; ++k) acc += H1s[lr][k] * w3r[k];
  H2s[lr][j] = fminf(fmaxf(acc, 0.f), 1.f);
  __syncthreads();

  if (j == 0) {
    float o = bo[0];
#pragma unroll
    for (int k = 0; k < 32; ++k) o += H2s[lr][k] * Wo[k];
    out[r] = fminf(fmaxf(o, 0.f), 1.f);
  }
}

// ---------------- launch ----------------
extern "C" void kernel_launch(void* const* d_in, const int* in_sizes, int n_in,
                              void* d_out, int out_size, void* d_ws, size_t ws_size,
                              hipStream_t stream) {
  const float* Ap  = (const float*)d_in[0];
  const float* Ao  = (const float*)d_in[1];
  const float* W1p = (const float*)d_in[2];
  const float* b1p = (const float*)d_in[3];
  const float* W1o = (const float*)d_in[4];
  const float* b1o = (const float*)d_in[5];
  const float* W2  = (const float*)d_in[6];
  const float* b2  = (const float*)d_in[7];
  const float* W3  = (const float*)d_in[8];
  const float* b3  = (const float*)d_in[9];
  const float* Wo  = (const float*)d_in[10];
  const float* bo  = (const float*)d_in[11];
  float* out = (float*)d_out;

  const size_t W16B = 2UL * NFEAT * K_DIM * 2;     // 41.9 MB
  const size_t COMB = (size_t)BATCH * 512 * 4;     // 4.2 MB
  auto need = [&](int s) {
    return W16B + (size_t)s * 2 * BATCH * NFEAT * 2 + COMB;  // fp16 partials
  };

  int S = 16;
  while (S > 1 && need(S) > ws_size) S >>= 1;

  char* ws = (char*)d_ws;
  f16* W16p = (f16*)ws;
  f16* W16o = W16p + (size_t)NFEAT * K_DIM;
  f16* partials = (f16*)(ws + W16B);
  float* combined = (float*)(ws + W16B + (size_t)S * 2 * BATCH * NFEAT * 2);

  convert_w<<<1024, 256, 0, stream>>>(W1p, W1o, W16p, W16o);

  int grid = (BATCH / 64) * S * 2;
  ft_gemm<<<grid, 512, 0, stream>>>(Ap, Ao, W16p, W16o, S, partials);

  reduce_bias<<<(BATCH * 256) / 256, 256, 0, stream>>>(partials, b1p, b1o, S, combined);

  mlp<<<BATCH / 8, 256, 0, stream>>>(combined, W2, b2, W3, b3, Wo, bo, out);
}